// Round 2
// baseline (243.913 us; speedup 1.0000x reference)
//
#include <hip/hip_runtime.h>

// Problem constants
constexpr int B = 32, C = 32, T = 2048, D = 512;
constexpr float ALPHA = 0.1f;
constexpr float BETA  = 0.9f;

// EWMA chunking
constexpr int CHUNK = 256;   // t-chunk per block
constexpr int SUB   = 32;    // t per thread
constexpr int HALO  = 128;   // beta^128 ~ 1.4e-6 -> error way below threshold
constexpr int PAD   = 515;   // LDS row pitch

// ---------------------------------------------------------------------------
// Kernel 1: W_comb[e,c] = sum_d W_lin[e,d]*W_ve[d,c];
//           b_comb[e]   = sum_d W_lin[e,d]*b_ve[d] + b_lin[e]
// ---------------------------------------------------------------------------
__global__ __launch_bounds__(256) void combine_weights(
    const float* __restrict__ W_ve, const float* __restrict__ b_ve,
    const float* __restrict__ W_lin, const float* __restrict__ b_lin,
    float* __restrict__ W_comb, float* __restrict__ b_comb) {
  int e  = blockIdx.x;
  int c  = threadIdx.x & 31;
  int ds = threadIdx.x >> 5;
  float acc = 0.f, accb = 0.f;
#pragma unroll 4
  for (int i = 0; i < 64; ++i) {
    int d = ds * 64 + i;
    float wl = W_lin[e * D + d];
    acc  += wl * W_ve[d * C + c];
    accb += wl * b_ve[d];
  }
  __shared__ float red[8][33];
  __shared__ float redb[8];
  red[ds][c] = acc;
  if (c == 0) redb[ds] = accb;
  __syncthreads();
  if (ds == 0) {
    float ssum = 0.f;
#pragma unroll
    for (int k = 0; k < 8; ++k) ssum += red[k][c];
    W_comb[e * C + c] = ssum;
    if (c == 0) {
      float sb = 0.f;
#pragma unroll
      for (int k = 0; k < 8; ++k) sb += redb[k];
      b_comb[e] = sb + b_lin[e];
    }
  }
}

// ---------------------------------------------------------------------------
// Kernel 2: channel-space diff + bidirectional EWMA (unchanged from R1).
// s[b][t][c] = 0.5*(fwdEWMA + bwdEWMA) of diff, halo-approximated.
// ---------------------------------------------------------------------------
__global__ __launch_bounds__(256) void diff_ewma(
    const float* __restrict__ x, float* __restrict__ sdst) {
  int b  = blockIdx.y;
  int t0 = blockIdx.x * CHUNK;
  int wlo = max(t0 - HALO - 1, 0);

  __shared__ float xl[C * PAD];
  const float* xb = x + (size_t)b * C * T;
  for (int idx = threadIdx.x; idx < C * 514; idx += 256) {
    int c  = idx / 514;
    int tt = idx - c * 514;
    int t  = wlo + tt;
    xl[c * PAD + tt] = (t < T) ? xb[c * T + t] : 0.f;
  }
  __syncthreads();

  int c   = threadIdx.x & 31;
  int sub = threadIdx.x >> 5;
  int ts  = t0 + sub * SUB;
  const float* xc = xl + c * PAD - wlo;

#define DD(t) ((t) == 0 ? 0.f : (xc[(t)] - xc[(t) - 1]))

  float lr[SUB];
  int st = max(ts - HALO, 0);
  float carry = DD(st);
  for (int t = st + 1; t < ts; ++t) carry = ALPHA * DD(t) + BETA * carry;
#pragma unroll
  for (int i = 0; i < SUB; ++i) {
    int t = ts + i;
    if (t > st) carry = ALPHA * DD(t) + BETA * carry;
    lr[i] = carry;
  }

  int en = min(ts + SUB - 1 + HALO, T - 1);
  float rcar = DD(en);
  for (int t = en - 1; t >= ts + SUB; --t) rcar = ALPHA * DD(t) + BETA * rcar;
  float* srow = sdst + ((size_t)b * T) * C + c;
#pragma unroll
  for (int i = SUB - 1; i >= 0; --i) {
    int t = ts + i;
    if (t < en) rcar = ALPHA * DD(t) + BETA * rcar;
    srow[(size_t)t * C] = 0.5f * (lr[i] + rcar);
  }
#undef DD
}

// ---------------------------------------------------------------------------
// Kernel 3 v2: out[b,t,e] = sum_c s[b,t,c]*W_comb[e,c] + b_comb[e]
//
// Old version issued 2048 block-uniform GLOBAL loads per thread (VMEM-issue
// bound). v2: stage the 8 KB s-tile in LDS (coalesced float4), broadcast
// ds_read_b128 thereafter (all-lanes-same-address = conflict-free, cheap).
// Thread owns 4 consecutive e (w rows in 128 VGPRs) -> 16 FMA per LDS read,
// float4 stores (contiguous 1 KB per wave-store).
// grid = (T/64, B), 256 threads: half = tid>>7 picks t-subtile of 32 rows,
// li = tid&127 picks e0 = li*4.
// ---------------------------------------------------------------------------
constexpr int TT = 64;  // t rows per block
__global__ __launch_bounds__(256) void out_gemm(
    const float* __restrict__ s, const float* __restrict__ W_comb,
    const float* __restrict__ b_comb, float* __restrict__ out) {
  int b  = blockIdx.y;
  int t0 = blockIdx.x * TT;

  __shared__ float st[TT * C];  // 8 KB
  // coalesced stage: 512 float4, 2 per thread
  const float4* sg = (const float4*)(s + ((size_t)b * T + t0) * C);
  float4* sl4 = (float4*)st;
  sl4[threadIdx.x]       = sg[threadIdx.x];
  sl4[threadIdx.x + 256] = sg[threadIdx.x + 256];

  int half = threadIdx.x >> 7;   // which 32-row t-subtile
  int li   = threadIdx.x & 127;
  int e0   = li * 4;

  // W rows for e0..e0+3 into registers (128 VGPRs), via float4
  float w[4][C];
#pragma unroll
  for (int j = 0; j < 4; ++j) {
    const float4* wr = (const float4*)(W_comb + (e0 + j) * C);
#pragma unroll
    for (int c4 = 0; c4 < C / 4; ++c4) {
      float4 wv = wr[c4];
      w[j][c4 * 4 + 0] = wv.x;
      w[j][c4 * 4 + 1] = wv.y;
      w[j][c4 * 4 + 2] = wv.z;
      w[j][c4 * 4 + 3] = wv.w;
    }
  }
  float bias[4];
#pragma unroll
  for (int j = 0; j < 4; ++j) bias[j] = b_comb[e0 + j];

  __syncthreads();

  const float* srow = st + half * 32 * C;
  float* orow = out + ((size_t)b * T + t0 + half * 32) * D + e0;

  for (int t = 0; t < 32; ++t) {
    float a[4], a2[4];
#pragma unroll
    for (int j = 0; j < 4; ++j) { a[j] = bias[j]; a2[j] = 0.f; }
    const float4* sr4 = (const float4*)(srow + t * C);
#pragma unroll
    for (int c4 = 0; c4 < C / 4; ++c4) {
      float4 sv = sr4[c4];  // broadcast ds_read_b128
      int c = c4 * 4;
#pragma unroll
      for (int j = 0; j < 4; ++j) {
        a[j]  += sv.x * w[j][c + 0];
        a2[j] += sv.y * w[j][c + 1];
        a[j]  += sv.z * w[j][c + 2];
        a2[j] += sv.w * w[j][c + 3];
      }
    }
    float4 o;
    o.x = a[0] + a2[0];
    o.y = a[1] + a2[1];
    o.z = a[2] + a2[2];
    o.w = a[3] + a2[3];
    *(float4*)(orow) = o;
    orow += D;
  }
}

// ---------------------------------------------------------------------------
extern "C" void kernel_launch(void* const* d_in, const int* in_sizes, int n_in,
                              void* d_out, int out_size, void* d_ws, size_t ws_size,
                              hipStream_t stream) {
  const float* x     = (const float*)d_in[0];  // [B,C,T]
  const float* W_ve  = (const float*)d_in[1];  // [D,C]
  const float* b_ve  = (const float*)d_in[2];  // [D]
  const float* W_lin = (const float*)d_in[3];  // [D,D]
  const float* b_lin = (const float*)d_in[4];  // [D]
  float* out = (float*)d_out;                  // [B,T,D]

  float* s      = (float*)d_ws;
  float* W_comb = s + (size_t)B * T * C;
  float* b_comb = W_comb + (size_t)D * C;

  combine_weights<<<D, 256, 0, stream>>>(W_ve, b_ve, W_lin, b_lin, W_comb, b_comb);
  diff_ewma<<<dim3(T / CHUNK, B), 256, 0, stream>>>(x, s);
  out_gemm<<<dim3(T / TT, B), 256, 0, stream>>>(s, W_comb, b_comb, out);
}

// Round 3
// 194.692 us; speedup vs baseline: 1.2528x; 1.2528x over previous
//
#include <hip/hip_runtime.h>

// Problem constants
constexpr int B = 32, C = 32, T = 2048, D = 512;
constexpr float ALPHA = 0.1f;
constexpr float BETA  = 0.9f;
constexpr float LOG2_BETA = -0.15200309344504997f;  // log2(0.9)

// Fused-kernel tiling
constexpr int CHUNK = 256;                 // t rows per block
constexpr int SUB   = 32;                  // t rows per thread (EWMA phase)
constexpr int HALO  = 128;                 // beta^128 ~ 1.4e-6
constexpr int WIN   = CHUNK + 2 * HALO + 2;  // 514 staged t per channel
constexpr int PAD   = WIN + 1;               // 515 LDS pitch

// ---------------------------------------------------------------------------
// Kernel 1: W_comb[e,c] = sum_d W_lin[e,d]*W_ve[d,c];
//           b_comb[e]   = sum_d W_lin[e,d]*b_ve[d] + b_lin[e]
// (out = smooth_C(diff) @ W_comb^T + b_comb -- EWMA commutes with Linear)
// ---------------------------------------------------------------------------
__global__ __launch_bounds__(256) void combine_weights(
    const float* __restrict__ W_ve, const float* __restrict__ b_ve,
    const float* __restrict__ W_lin, const float* __restrict__ b_lin,
    float* __restrict__ W_comb, float* __restrict__ b_comb) {
  int e  = blockIdx.x;
  int c  = threadIdx.x & 31;
  int ds = threadIdx.x >> 5;
  float acc = 0.f, accb = 0.f;
#pragma unroll 4
  for (int i = 0; i < 64; ++i) {
    int d = ds * 64 + i;
    float wl = W_lin[e * D + d];
    acc  += wl * W_ve[d * C + c];
    accb += wl * b_ve[d];
  }
  __shared__ float red[8][33];
  __shared__ float redb[8];
  red[ds][c] = acc;
  if (c == 0) redb[ds] = accb;
  __syncthreads();
  if (ds == 0) {
    float ssum = 0.f;
#pragma unroll
    for (int k = 0; k < 8; ++k) ssum += red[k][c];
    W_comb[e * C + c] = ssum;
    if (c == 0) {
      float sb = 0.f;
#pragma unroll
      for (int k = 0; k < 8; ++k) sb += redb[k];
      b_comb[e] = sb + b_lin[e];
    }
  }
}

// ---------------------------------------------------------------------------
// Kernel 2 (fused): diff + bidirectional EWMA in channel space + K=32 GEMM.
// grid = (T/CHUNK=8, B=32) = 256 blocks, 256 threads.
//
// Phase A: stage x[b, :, window] into LDS with clamped t-index, so
//          DD(t) = xl[t]-xl[t-1] is exactly 0 for t<=0 and t>=T.
// Phase B: per-thread (c = tid&31, sub = tid>>5, 32 t each):
//          fwd+bwd halo carries (branchless, interleaved chains), then
//          main scans; right edge fixed exactly via
//          rl[t] = rl'[t] + beta^(T-t) * d[T-1]   (underflows to 0 mid-seq).
// Phase C: s-tile (CHUNK x C, 32 KB) written into the reused staging LDS;
//          GEMM: thread owns e0=4*(tid&127) (W rows in 128 VGPRs),
//          half=tid>>7 picks 128-t subtile; broadcast ds_read_b128,
//          128 FMA per t, float4 coalesced stores.
// ---------------------------------------------------------------------------
__global__ __launch_bounds__(256) void fused_main(
    const float* __restrict__ x, const float* __restrict__ W_comb,
    const float* __restrict__ b_comb, float* __restrict__ out) {
  int b  = blockIdx.y;
  int t0 = blockIdx.x * CHUNK;
  int wlo = t0 - HALO - 1;  // staged window covers global t in [wlo, wlo+WIN)

  __shared__ float xl[C * PAD];  // 65.9 KB; reused as s-tile in phase C
  const float* xb = x + (size_t)b * C * T;

  // ---- Phase A: clamped staging ----
  for (int idx = threadIdx.x; idx < C * WIN; idx += 256) {
    int c  = idx / WIN;  // compile-time divisor
    int tt = idx - c * WIN;
    int t  = wlo + tt;
    t = min(max(t, 0), T - 1);
    xl[c * PAD + tt] = xb[c * T + t];
  }

  // W rows + bias into registers (overlaps staging; L2-broadcast after warmup)
  int li   = threadIdx.x & 127;
  int half = threadIdx.x >> 7;
  int e0   = li * 4;
  float w[4][C], bias[4];
#pragma unroll
  for (int j = 0; j < 4; ++j) {
    const float4* wr = (const float4*)(W_comb + (e0 + j) * C);
#pragma unroll
    for (int c4 = 0; c4 < C / 4; ++c4) {
      float4 wv = wr[c4];
      w[j][c4 * 4 + 0] = wv.x;
      w[j][c4 * 4 + 1] = wv.y;
      w[j][c4 * 4 + 2] = wv.z;
      w[j][c4 * 4 + 3] = wv.w;
    }
    bias[j] = b_comb[e0 + j];
  }
  __syncthreads();

  // ---- Phase B: EWMA ----
  int c   = threadIdx.x & 31;
  int sub = threadIdx.x >> 5;
  int ts  = t0 + sub * SUB;
  int te  = ts + SUB - 1;
  const float* xc = xl + c * PAD - wlo;  // index directly by global t

#define DD(t) (xc[(t)] - xc[(t) - 1])

  // interleaved fwd/bwd halo carries (2 independent chains)
  float fc = 0.f, bc = 0.f;
#pragma unroll 8
  for (int k = HALO; k >= 1; --k) {
    float df = DD(ts - k);
    float db = DD(te + k);
    fc = ALPHA * df + BETA * fc;
    bc = ALPHA * db + BETA * bc;
  }

  // fwd main scan
  float lr[SUB];
#pragma unroll
  for (int i = 0; i < SUB; ++i) {
    fc = ALPHA * DD(ts + i) + BETA * fc;
    lr[i] = fc;
  }

  // bwd main scan with exact right-edge correction, combine in regs
  float dlast = xb[c * T + (T - 1)] - xb[c * T + (T - 2)];
  float fcor  = exp2f((float)(T - te) * LOG2_BETA);  // beta^(T-te)
#pragma unroll
  for (int i = SUB - 1; i >= 0; --i) {
    bc = ALPHA * DD(ts + i) + BETA * bc;
    lr[i] = 0.5f * (lr[i] + bc + fcor * dlast);
    fcor *= BETA;
  }
#undef DD

  __syncthreads();  // all EWMA reads of xl done -> safe to overwrite

  // ---- Phase C: write s-tile into reused LDS, then GEMM ----
  float* sbuf = xl;  // s[tloc*C + c], tloc in [0, CHUNK)
  {
    int tbase = sub * SUB;
#pragma unroll
    for (int i = 0; i < SUB; ++i) sbuf[(tbase + i) * C + c] = lr[i];
  }
  __syncthreads();

  const float* srow = sbuf + half * (CHUNK / 2) * C;
  float* orow = out + ((size_t)b * T + t0 + half * (CHUNK / 2)) * D + e0;

  for (int t = 0; t < CHUNK / 2; ++t) {
    float a[4], a2[4];
#pragma unroll
    for (int j = 0; j < 4; ++j) { a[j] = bias[j]; a2[j] = 0.f; }
    const float4* sr4 = (const float4*)(srow + t * C);
#pragma unroll
    for (int c4 = 0; c4 < C / 4; ++c4) {
      float4 sv = sr4[c4];  // broadcast ds_read_b128
      int cc = c4 * 4;
#pragma unroll
      for (int j = 0; j < 4; ++j) {
        a[j]  += sv.x * w[j][cc + 0];
        a2[j] += sv.y * w[j][cc + 1];
        a[j]  += sv.z * w[j][cc + 2];
        a2[j] += sv.w * w[j][cc + 3];
      }
    }
    float4 o;
    o.x = a[0] + a2[0];
    o.y = a[1] + a2[1];
    o.z = a[2] + a2[2];
    o.w = a[3] + a2[3];
    *(float4*)orow = o;
    orow += D;
  }
}

// ---------------------------------------------------------------------------
extern "C" void kernel_launch(void* const* d_in, const int* in_sizes, int n_in,
                              void* d_out, int out_size, void* d_ws, size_t ws_size,
                              hipStream_t stream) {
  const float* x     = (const float*)d_in[0];  // [B,C,T]
  const float* W_ve  = (const float*)d_in[1];  // [D,C]
  const float* b_ve  = (const float*)d_in[2];  // [D]
  const float* W_lin = (const float*)d_in[3];  // [D,D]
  const float* b_lin = (const float*)d_in[4];  // [D]
  float* out = (float*)d_out;                  // [B,T,D]

  // workspace: W_comb [D*C], b_comb [D]
  float* W_comb = (float*)d_ws;
  float* b_comb = W_comb + (size_t)D * C;

  combine_weights<<<D, 256, 0, stream>>>(W_ve, b_ve, W_lin, b_lin, W_comb, b_comb);
  fused_main<<<dim3(T / CHUNK, B), 256, 0, stream>>>(x, W_comb, b_comb, out);
}

// Round 5
// 180.333 us; speedup vs baseline: 1.3526x; 1.0796x over previous
//
#include <hip/hip_runtime.h>

// Problem constants
constexpr int B = 32, C = 32, T = 2048, D = 512;
constexpr float ALPHA = 0.1f;
constexpr float BETA  = 0.9f;
constexpr float LOG2_BETA = -0.15200309344504997f;  // log2(0.9)

// Native 4-float vector for __builtin_nontemporal_store (HIP float4 is a
// struct type the builtin rejects).
typedef float floatx4 __attribute__((ext_vector_type(4)));

// Fused-kernel tiling. CHUNK=128: LDS = 32*387*4 = 49.5 KB -> 3 blocks/CU
// resident, so one block's store-bound GEMM overlaps the next block's
// staging+EWMA (at CHUNK=256/66KB we were 1 block/CU: phases serialized).
constexpr int CHUNK = 128;                   // t rows per block
constexpr int SUB   = 16;                    // t rows per thread (EWMA phase)
constexpr int HALO  = 128;                   // beta^128 ~ 1.4e-6
constexpr int WIN   = CHUNK + 2 * HALO + 2;  // 386 staged t per channel
constexpr int PAD   = WIN + 1;               // 387 LDS pitch

// ---------------------------------------------------------------------------
// Kernel 1: W_comb[e,c] = sum_d W_lin[e,d]*W_ve[d,c];
//           b_comb[e]   = sum_d W_lin[e,d]*b_ve[d] + b_lin[e]
// (out = smooth_C(diff) @ W_comb^T + b_comb -- EWMA commutes with Linear)
// ---------------------------------------------------------------------------
__global__ __launch_bounds__(256) void combine_weights(
    const float* __restrict__ W_ve, const float* __restrict__ b_ve,
    const float* __restrict__ W_lin, const float* __restrict__ b_lin,
    float* __restrict__ W_comb, float* __restrict__ b_comb) {
  int e  = blockIdx.x;
  int c  = threadIdx.x & 31;
  int ds = threadIdx.x >> 5;
  float acc = 0.f, accb = 0.f;
#pragma unroll 4
  for (int i = 0; i < 64; ++i) {
    int d = ds * 64 + i;
    float wl = W_lin[e * D + d];
    acc  += wl * W_ve[d * C + c];
    accb += wl * b_ve[d];
  }
  __shared__ float red[8][33];
  __shared__ float redb[8];
  red[ds][c] = acc;
  if (c == 0) redb[ds] = accb;
  __syncthreads();
  if (ds == 0) {
    float ssum = 0.f;
#pragma unroll
    for (int k = 0; k < 8; ++k) ssum += red[k][c];
    W_comb[e * C + c] = ssum;
    if (c == 0) {
      float sb = 0.f;
#pragma unroll
      for (int k = 0; k < 8; ++k) sb += redb[k];
      b_comb[e] = sb + b_lin[e];
    }
  }
}

// ---------------------------------------------------------------------------
// Kernel 2 (fused): diff + bidirectional EWMA in channel space + K=32 GEMM.
// grid = (T/CHUNK=16, B=32) = 512 blocks, 256 threads.
//
// Phase A: stage x[b, :, window] into LDS with clamped t-index, so
//          DD(t) = xl[t]-xl[t-1] is exactly 0 for t<=0 and t>=T.
// Phase B: per-thread (c = tid&31, sub = tid>>5, SUB t each):
//          fwd+bwd halo carries (branchless, interleaved chains), main
//          scans; exact right-edge fix rl[t] += beta^(T-t)*d[T-1].
// Phase C: s-tile (CHUNK x C, 16 KB) into reused staging LDS; GEMM:
//          thread owns e0=4*(tid&127) (W rows in 128 VGPRs), half=tid>>7
//          picks 64-t subtile; broadcast ds_read_b128, nontemporal
//          float4 stores (out is write-once, >> L2).
// ---------------------------------------------------------------------------
__global__ __launch_bounds__(256) void fused_main(
    const float* __restrict__ x, const float* __restrict__ W_comb,
    const float* __restrict__ b_comb, float* __restrict__ out) {
  int b  = blockIdx.y;
  int t0 = blockIdx.x * CHUNK;
  int wlo = t0 - HALO - 1;  // staged window covers global t in [wlo, wlo+WIN)

  __shared__ float xl[C * PAD];  // 49.5 KB; reused as s-tile in phase C
  const float* xb = x + (size_t)b * C * T;

  // ---- Phase A: clamped staging ----
  for (int idx = threadIdx.x; idx < C * WIN; idx += 256) {
    int c  = idx / WIN;  // compile-time divisor
    int tt = idx - c * WIN;
    int t  = wlo + tt;
    t = min(max(t, 0), T - 1);
    xl[c * PAD + tt] = xb[c * T + t];
  }

  // W rows + bias into registers (overlaps staging latency)
  int li   = threadIdx.x & 127;
  int half = threadIdx.x >> 7;
  int e0   = li * 4;
  float w[4][C], bias[4];
#pragma unroll
  for (int j = 0; j < 4; ++j) {
    const float4* wr = (const float4*)(W_comb + (e0 + j) * C);
#pragma unroll
    for (int c4 = 0; c4 < C / 4; ++c4) {
      float4 wv = wr[c4];
      w[j][c4 * 4 + 0] = wv.x;
      w[j][c4 * 4 + 1] = wv.y;
      w[j][c4 * 4 + 2] = wv.z;
      w[j][c4 * 4 + 3] = wv.w;
    }
    bias[j] = b_comb[e0 + j];
  }
  __syncthreads();

  // ---- Phase B: EWMA ----
  int c   = threadIdx.x & 31;
  int sub = threadIdx.x >> 5;
  int ts  = t0 + sub * SUB;
  int te  = ts + SUB - 1;
  const float* xc = xl + c * PAD - wlo;  // index directly by global t

#define DD(t) (xc[(t)] - xc[(t) - 1])

  // interleaved fwd/bwd halo carries (2 independent chains)
  float fc = 0.f, bc = 0.f;
#pragma unroll 8
  for (int k = HALO; k >= 1; --k) {
    float df = DD(ts - k);
    float db = DD(te + k);
    fc = ALPHA * df + BETA * fc;
    bc = ALPHA * db + BETA * bc;
  }

  // fwd main scan
  float lr[SUB];
#pragma unroll
  for (int i = 0; i < SUB; ++i) {
    fc = ALPHA * DD(ts + i) + BETA * fc;
    lr[i] = fc;
  }

  // bwd main scan with exact right-edge correction, combine in regs
  float dlast = xb[c * T + (T - 1)] - xb[c * T + (T - 2)];
  float fcor  = exp2f((float)(T - te) * LOG2_BETA);  // beta^(T-te)
#pragma unroll
  for (int i = SUB - 1; i >= 0; --i) {
    bc = ALPHA * DD(ts + i) + BETA * bc;
    lr[i] = 0.5f * (lr[i] + bc + fcor * dlast);
    fcor *= BETA;
  }
#undef DD

  __syncthreads();  // all EWMA reads of xl done -> safe to overwrite

  // ---- Phase C: s-tile into reused LDS, then GEMM ----
  float* sbuf = xl;  // s[tloc*C + c], tloc in [0, CHUNK)
  {
    int tbase = sub * SUB;
#pragma unroll
    for (int i = 0; i < SUB; ++i) sbuf[(tbase + i) * C + c] = lr[i];
  }
  __syncthreads();

  const float* srow = sbuf + half * (CHUNK / 2) * C;
  float* orow = out + ((size_t)b * T + t0 + half * (CHUNK / 2)) * D + e0;

  for (int t = 0; t < CHUNK / 2; ++t) {
    float a[4], a2[4];
#pragma unroll
    for (int j = 0; j < 4; ++j) { a[j] = bias[j]; a2[j] = 0.f; }
    const float4* sr4 = (const float4*)(srow + t * C);
#pragma unroll
    for (int c4 = 0; c4 < C / 4; ++c4) {
      float4 sv = sr4[c4];  // broadcast ds_read_b128
      int cc = c4 * 4;
#pragma unroll
      for (int j = 0; j < 4; ++j) {
        a[j]  += sv.x * w[j][cc + 0];
        a2[j] += sv.y * w[j][cc + 1];
        a[j]  += sv.z * w[j][cc + 2];
        a2[j] += sv.w * w[j][cc + 3];
      }
    }
    floatx4 o;
    o.x = a[0] + a2[0];
    o.y = a[1] + a2[1];
    o.z = a[2] + a2[2];
    o.w = a[3] + a2[3];
    __builtin_nontemporal_store(o, (floatx4*)orow);  // write-once stream
    orow += D;
  }
}

// ---------------------------------------------------------------------------
extern "C" void kernel_launch(void* const* d_in, const int* in_sizes, int n_in,
                              void* d_out, int out_size, void* d_ws, size_t ws_size,
                              hipStream_t stream) {
  const float* x     = (const float*)d_in[0];  // [B,C,T]
  const float* W_ve  = (const float*)d_in[1];  // [D,C]
  const float* b_ve  = (const float*)d_in[2];  // [D]
  const float* W_lin = (const float*)d_in[3];  // [D,D]
  const float* b_lin = (const float*)d_in[4];  // [D]
  float* out = (float*)d_out;                  // [B,T,D]

  // workspace: W_comb [D*C], b_comb [D]
  float* W_comb = (float*)d_ws;
  float* b_comb = W_comb + (size_t)D * C;

  combine_weights<<<D, 256, 0, stream>>>(W_ve, b_ve, W_lin, b_lin, W_comb, b_comb);
  fused_main<<<dim3(T / CHUNK, B), 256, 0, stream>>>(x, W_comb, b_comb, out);
}